// Round 1
// baseline (998.140 us; speedup 1.0000x reference)
//
#include <hip/hip_runtime.h>
#include <hip/hip_bf16.h>
#include <cstdint>
#include <cstddef>

typedef __attribute__((ext_vector_type(8))) short short8;   // 8 bf16 = 4 VGPRs (MFMA A/B frag)
typedef __attribute__((ext_vector_type(4))) float f32x4;    // MFMA C/D frag

__device__ __forceinline__ unsigned short f2bf(float f) {
  unsigned u = __float_as_uint(f);
  unsigned r = (u + 0x7fffu + ((u >> 16) & 1u)) >> 16;   // RNE
  return (unsigned short)r;
}
__device__ __forceinline__ float bf2f(unsigned short b) {
  return __uint_as_float(((unsigned)b) << 16);
}
// order-preserving float -> uint key for atomicMax (0 sentinel < every real key)
__device__ __forceinline__ unsigned fkey(float f) {
  unsigned b = __float_as_uint(f);
  return (b & 0x80000000u) ? ~b : (b | 0x80000000u);
}

// ---------------------------------------------------------------------------
// Pack W1a [256(k) x 256(col)] fp32 -> bf16 in MFMA-B-fragment order:
// packedB[((s*32 + kk*4+quad)*64 + n)*8 + j] = bf16(W1a[kk*32+quad*8+j][s*64+n])
// so a lane's b-frag is one contiguous 16B read (conflict-free ds_read_b128).
// ---------------------------------------------------------------------------
__global__ __launch_bounds__(256)
void prep_b_kernel(const float* __restrict__ W1a, unsigned short* __restrict__ packedB) {
  int idx = blockIdx.x * 256 + threadIdx.x;   // 0..65535
  int j  = idx & 7;
  int n  = (idx >> 3) & 63;
  int kq = (idx >> 9) & 31;                   // kk*4 + quad
  int s  = idx >> 14;                         // column stage (64 cols each)
  int k  = (kq >> 2) * 32 + (kq & 3) * 8 + j;
  int col = s * 64 + n;
  packedB[idx] = f2bf(W1a[k * 256 + col]);
}

// ---------------------------------------------------------------------------
// Fused: bf16 MFMA GEMM (x @ W1a) -> relu -> @W2a -> sigmoid -> aw,
// then segment pooling (att-sum / sum / max / count) via atomics.
// 64 nodes per block, 4 waves x 16 rows each.
// ---------------------------------------------------------------------------
__global__ __launch_bounds__(256, 2)
void phase_a_kernel(const float* __restrict__ x, const int* __restrict__ batch,
                    const unsigned short* __restrict__ packedB,
                    const float* __restrict__ b1a, const float* __restrict__ W2a,
                    const float* __restrict__ b2a,
                    float* __restrict__ attbuf, float* __restrict__ sumbuf,
                    unsigned* __restrict__ maxkey, float* __restrict__ cntbuf,
                    int nnodes) {
  __shared__ __align__(16) unsigned short sX[64][264];   // bf16 x tile, +8 pad per row
  __shared__ __align__(16) unsigned short sB[64 * 256];  // one 64-col stage of packed W1a
  __shared__ float sAw[64];
  __shared__ int   sBatch[64];
  __shared__ float sB1a[256];
  __shared__ float sW2a[256];

  const int t = threadIdx.x;
  const int lane = t & 63;
  const int w = t >> 6;          // wave id: owns node rows w*16..w*16+15
  const int m = lane & 15;
  const int quad = lane >> 4;
  const int block0 = blockIdx.x * 64;
  const int nvalid = min(64, nnodes - block0);

  sB1a[t] = b1a[t];
  sW2a[t] = W2a[t];
  if (t < 64) sBatch[t] = (t < nvalid) ? batch[block0 + t] : -1;

  // stage x tile (64 x 256 fp32) -> bf16 LDS, coalesced float4 loads
  #pragma unroll
  for (int it = 0; it < 16; ++it) {
    int idx = it * 256 + t;       // float4 slot 0..4095
    int row = idx >> 6;
    int c4  = idx & 63;
    float4 v = make_float4(0.f, 0.f, 0.f, 0.f);
    if (block0 + row < nnodes)
      v = reinterpret_cast<const float4*>(x)[(size_t)(block0 + row) * 64 + c4];
    ushort4 h;
    h.x = f2bf(v.x); h.y = f2bf(v.y); h.z = f2bf(v.z); h.w = f2bf(v.w);
    *reinterpret_cast<ushort4*>(&sX[row][c4 * 4]) = h;
  }

  const float b2 = b2a[0];
  float part[4] = {0.f, 0.f, 0.f, 0.f};   // per-lane partial of relu(h)·W2a for rows quad*4+r

  for (int s = 0; s < 4; ++s) {
    __syncthreads();   // also covers sX/sB1a/sW2a/sBatch writes on s==0
    {
      const uint4* src = reinterpret_cast<const uint4*>(packedB + (size_t)s * 16384);
      uint4* dst = reinterpret_cast<uint4*>(sB);
      #pragma unroll
      for (int i = 0; i < 8; ++i) dst[i * 256 + t] = src[i * 256 + t];
    }
    __syncthreads();

    f32x4 acc0 = {0,0,0,0}, acc1 = {0,0,0,0}, acc2 = {0,0,0,0}, acc3 = {0,0,0,0};
    #pragma unroll
    for (int kk = 0; kk < 8; ++kk) {
      short8 af = *reinterpret_cast<const short8*>(&sX[w * 16 + m][kk * 32 + quad * 8]);
      const unsigned short* bbase = &sB[((kk * 4 + quad) * 64 + m) * 8];
      short8 bf0 = *reinterpret_cast<const short8*>(bbase);
      short8 bf1 = *reinterpret_cast<const short8*>(bbase + 16 * 8);
      short8 bf2 = *reinterpret_cast<const short8*>(bbase + 32 * 8);
      short8 bf3 = *reinterpret_cast<const short8*>(bbase + 48 * 8);
      acc0 = __builtin_amdgcn_mfma_f32_16x16x32_bf16(af, bf0, acc0, 0, 0, 0);
      acc1 = __builtin_amdgcn_mfma_f32_16x16x32_bf16(af, bf1, acc1, 0, 0, 0);
      acc2 = __builtin_amdgcn_mfma_f32_16x16x32_bf16(af, bf2, acc2, 0, 0, 0);
      acc3 = __builtin_amdgcn_mfma_f32_16x16x32_bf16(af, bf3, acc3, 0, 0, 0);
    }
    // fold this stage's 64 hidden cols into the attention-score partials
    #pragma unroll
    for (int r = 0; r < 4; ++r) {
      int colb = s * 64 + m;
      float h0 = fmaxf(acc0[r] + sB1a[colb],      0.f);
      float h1 = fmaxf(acc1[r] + sB1a[colb + 16], 0.f);
      float h2 = fmaxf(acc2[r] + sB1a[colb + 32], 0.f);
      float h3 = fmaxf(acc3[r] + sB1a[colb + 48], 0.f);
      part[r] += h0 * sW2a[colb] + h1 * sW2a[colb + 16] +
                 h2 * sW2a[colb + 32] + h3 * sW2a[colb + 48];
    }
  }

  // reduce over the 16 m-lanes (cols), then sigmoid -> aw per node
  #pragma unroll
  for (int off = 1; off < 16; off <<= 1) {
    #pragma unroll
    for (int r = 0; r < 4; ++r) part[r] += __shfl_xor(part[r], off, 64);
  }
  if (m == 0) {
    #pragma unroll
    for (int r = 0; r < 4; ++r) {
      float sc = part[r] + b2;
      sAw[w * 16 + quad * 4 + r] = 1.f / (1.f + __expf(-sc));
    }
  }
  __syncthreads();

  // segment pooling: thread t owns channel t; batch sorted -> run-length flush
  float a_att = 0.f, a_sum = 0.f, a_max = -INFINITY;
  int seg = sBatch[0];
  int runlen = 0;
  for (int i = 0; i < nvalid; ++i) {
    int b = sBatch[i];
    if (b != seg) {
      atomicAdd(&attbuf[(size_t)seg * 256 + t], a_att);
      atomicAdd(&sumbuf[(size_t)seg * 256 + t], a_sum);
      atomicMax(&maxkey[(size_t)seg * 256 + t], fkey(a_max));
      if (t == 0) atomicAdd(&cntbuf[seg], (float)runlen);
      a_att = 0.f; a_sum = 0.f; a_max = -INFINITY; runlen = 0; seg = b;
    }
    float xv = bf2f(sX[i][t]);
    a_sum += xv;
    a_att += xv * sAw[i];
    a_max = fmaxf(a_max, xv);
    ++runlen;
  }
  atomicAdd(&attbuf[(size_t)seg * 256 + t], a_att);
  atomicAdd(&sumbuf[(size_t)seg * 256 + t], a_sum);
  atomicMax(&maxkey[(size_t)seg * 256 + t], fkey(a_max));
  if (t == 0) atomicAdd(&cntbuf[seg], (float)runlen);
}

// ---------------------------------------------------------------------------
// Final MLP: out[g] = relu(comb[g] @ W1f + b1f) @ W2f + b2f, 8 graphs/block,
// rank-1-update formulation (coalesced weight reads, LDS broadcast of comb).
// ---------------------------------------------------------------------------
__global__ __launch_bounds__(256, 2)
void final_mlp_kernel(const float* __restrict__ attbuf, const float* __restrict__ sumbuf,
                      const unsigned* __restrict__ maxkey, const float* __restrict__ cntbuf,
                      const float* __restrict__ W1f, const float* __restrict__ b1f,
                      const float* __restrict__ W2f, const float* __restrict__ b2f,
                      float* __restrict__ out) {
  __shared__ float sComb[8 * 768];
  __shared__ float sHid[8 * 256];
  const int t = threadIdx.x;
  const int g0 = blockIdx.x * 8;

  for (int idx = t; idx < 8 * 768; idx += 256) {
    int g = idx / 768;
    int k = idx - g * 768;
    int gg = g0 + g;
    float cnt = cntbuf[gg];
    float v;
    if (k < 256) {
      v = attbuf[(size_t)gg * 256 + k];
    } else if (k < 512) {
      v = sumbuf[(size_t)gg * 256 + (k - 256)] / fmaxf(cnt, 1.f);
    } else {
      unsigned u = maxkey[(size_t)gg * 256 + (k - 512)];
      unsigned b = (u & 0x80000000u) ? (u & 0x7fffffffu) : ~u;
      v = (cnt > 0.f) ? __uint_as_float(b) : 0.f;   // empty segment -> 0
    }
    sComb[idx] = v;
  }
  __syncthreads();

  float acc[8] = {0,0,0,0,0,0,0,0};
  for (int k = 0; k < 768; ++k) {
    float wv = W1f[k * 256 + t];
    #pragma unroll
    for (int g = 0; g < 8; ++g) acc[g] = fmaf(sComb[g * 768 + k], wv, acc[g]);
  }
  float bb = b1f[t];
  #pragma unroll
  for (int g = 0; g < 8; ++g) sHid[g * 256 + t] = fmaxf(acc[g] + bb, 0.f);
  __syncthreads();

  float acc2[8] = {0,0,0,0,0,0,0,0};
  for (int k = 0; k < 256; ++k) {
    float wv = W2f[k * 256 + t];
    #pragma unroll
    for (int g = 0; g < 8; ++g) acc2[g] = fmaf(sHid[g * 256 + k], wv, acc2[g]);
  }
  float bo = b2f[t];
  #pragma unroll
  for (int g = 0; g < 8; ++g) out[(size_t)(g0 + g) * 256 + t] = acc2[g] + bo;
}

// ---------------------------------------------------------------------------
extern "C" void kernel_launch(void* const* d_in, const int* in_sizes, int n_in,
                              void* d_out, int out_size, void* d_ws, size_t ws_size,
                              hipStream_t stream) {
  const float* x   = (const float*)d_in[0];
  const int* batch = (const int*)d_in[1];
  const float* W1a = (const float*)d_in[2];
  const float* b1a = (const float*)d_in[3];
  const float* W2a = (const float*)d_in[4];
  const float* b2a = (const float*)d_in[5];
  const float* W1f = (const float*)d_in[6];
  const float* b1f = (const float*)d_in[7];
  const float* W2f = (const float*)d_in[8];
  const float* b2f = (const float*)d_in[9];
  float* out = (float*)d_out;

  const int N = in_sizes[0] / 256;
  const int G = out_size / 256;

  char* ws = (char*)d_ws;
  float* attbuf = (float*)ws;
  float* sumbuf = attbuf + (size_t)G * 256;
  unsigned* maxkey = (unsigned*)(sumbuf + (size_t)G * 256);
  float* cntbuf = (float*)(maxkey + (size_t)G * 256);
  unsigned short* packedB = (unsigned short*)(cntbuf + G);

  size_t zero_bytes = ((size_t)G * 256 * 3 + G) * sizeof(float);
  hipMemsetAsync(d_ws, 0, zero_bytes, stream);

  prep_b_kernel<<<256, 256, 0, stream>>>(W1a, packedB);

  int nblocks = (N + 63) / 64;
  phase_a_kernel<<<nblocks, 256, 0, stream>>>(x, batch, packedB, b1a, W2a, b2a,
                                              attbuf, sumbuf, maxkey, cntbuf, N);

  final_mlp_kernel<<<G / 8, 256, 0, stream>>>(attbuf, sumbuf, maxkey, cntbuf,
                                              W1f, b1f, W2f, b2f, out);
}

// Round 2
// 949.982 us; speedup vs baseline: 1.0507x; 1.0507x over previous
//
#include <hip/hip_runtime.h>
#include <hip/hip_bf16.h>
#include <cstdint>
#include <cstddef>

typedef __attribute__((ext_vector_type(8))) short short8;   // 8 bf16 = 4 VGPRs (MFMA A/B frag)
typedef __attribute__((ext_vector_type(4))) float f32x4;    // MFMA C/D frag

__device__ __forceinline__ unsigned short f2bf(float f) {
  unsigned u = __float_as_uint(f);
  unsigned r = (u + 0x7fffu + ((u >> 16) & 1u)) >> 16;   // RNE
  return (unsigned short)r;
}
__device__ __forceinline__ float bf2f(unsigned short b) {
  return __uint_as_float(((unsigned)b) << 16);
}
// order-preserving float -> uint key for atomicMax (0 sentinel < every real key)
__device__ __forceinline__ unsigned fkey(float f) {
  unsigned b = __float_as_uint(f);
  return (b & 0x80000000u) ? ~b : (b | 0x80000000u);
}

// ---------------------------------------------------------------------------
// Pack W1a [256(k) x 256(col)] fp32 -> bf16 in MFMA-B-fragment order:
// packedB[((s*32 + kk*4+quad)*64 + n)*8 + j] = bf16(W1a[kk*32+quad*8+j][s*64+n])
// (s = col>>6 stage, n = col&63). A lane's b-frag is one contiguous 16B read.
// ---------------------------------------------------------------------------
__global__ __launch_bounds__(256)
void prep_b_kernel(const float* __restrict__ W1a, unsigned short* __restrict__ packedB) {
  int idx = blockIdx.x * 256 + threadIdx.x;   // 0..65535
  int j  = idx & 7;
  int n  = (idx >> 3) & 63;
  int kq = (idx >> 9) & 31;                   // kk*4 + quad
  int s  = idx >> 14;                         // column stage (64 cols each)
  int k  = (kq >> 2) * 32 + (kq & 3) * 8 + j;
  int col = s * 64 + n;
  packedB[idx] = f2bf(W1a[k * 256 + col]);
}

// ---------------------------------------------------------------------------
// Persistent fused phase-A: bf16 MFMA GEMM (x @ W1a) -> relu -> @W2a -> sigmoid
// -> aw, then segment pooling via atomics. W1a fragments live in REGISTERS for
// the whole kernel (wave w owns hidden cols [w*64, w*64+64): 8kk x 4nb frags =
// 128 VGPRs). 512 blocks x 256 thr loop over 64-node tiles.
// ---------------------------------------------------------------------------
__global__ __launch_bounds__(256, 2)
void phase_a_kernel(const float* __restrict__ x, const int* __restrict__ batch,
                    const unsigned short* __restrict__ packedB,
                    const float* __restrict__ b1a, const float* __restrict__ W2a,
                    const float* __restrict__ b2a,
                    float* __restrict__ attbuf, float* __restrict__ sumbuf,
                    unsigned* __restrict__ maxkey, float* __restrict__ cntbuf,
                    int nnodes, int ntiles) {
  __shared__ __align__(16) unsigned short sX[64][264];   // bf16 x tile, +8 pad/row
  __shared__ float sScoreP[4][64];                       // per-wave score partials
  __shared__ float sAw[64];
  __shared__ int   sBatch[64];

  const int t = threadIdx.x;
  const int lane = t & 63;
  const int w = t >> 6;          // wave id: owns hidden cols w*64 .. w*64+63
  const int m = lane & 15;
  const int quad = lane >> 4;

  // --- resident B fragments (once per block; L2-hot) ---
  short8 Bfrag[8][4];
  #pragma unroll
  for (int kk = 0; kk < 8; ++kk) {
    #pragma unroll
    for (int nb = 0; nb < 4; ++nb) {
      Bfrag[kk][nb] = *reinterpret_cast<const short8*>(
          packedB + (size_t)((w * 32 + kk * 4 + quad) * 64 + nb * 16 + m) * 8);
    }
  }
  float b1r[4], w2r[4];
  #pragma unroll
  for (int nb = 0; nb < 4; ++nb) {
    int col = w * 64 + nb * 16 + m;
    b1r[nb] = b1a[col];
    w2r[nb] = W2a[col];
  }
  const float b2 = b2a[0];

  for (int tile = blockIdx.x; tile < ntiles; tile += gridDim.x) {
    const int block0 = tile * 64;
    const int nvalid = min(64, nnodes - block0);

    if (t < 64) sBatch[t] = (t < nvalid) ? batch[block0 + t] : -1;

    // stage x tile (64 x 256 fp32) -> bf16 LDS, coalesced float4 loads
    #pragma unroll
    for (int it = 0; it < 16; ++it) {
      int idx = it * 256 + t;       // float4 slot 0..4095
      int row = idx >> 6;
      int c4  = idx & 63;
      float4 v = make_float4(0.f, 0.f, 0.f, 0.f);
      if (block0 + row < nnodes)
        v = reinterpret_cast<const float4*>(x)[(size_t)(block0 + row) * 64 + c4];
      ushort4 h;
      h.x = f2bf(v.x); h.y = f2bf(v.y); h.z = f2bf(v.z); h.w = f2bf(v.w);
      *reinterpret_cast<ushort4*>(&sX[row][c4 * 4]) = h;
    }
    __syncthreads();

    // MFMA: wave w computes h[:, w*64 : w*64+64] for all 64 nodes, folds into
    // partial attention scores.
    #pragma unroll
    for (int mt = 0; mt < 4; ++mt) {
      f32x4 acc[4] = {{0,0,0,0},{0,0,0,0},{0,0,0,0},{0,0,0,0}};
      #pragma unroll
      for (int kk = 0; kk < 8; ++kk) {
        short8 af = *reinterpret_cast<const short8*>(&sX[mt * 16 + m][kk * 32 + quad * 8]);
        #pragma unroll
        for (int nb = 0; nb < 4; ++nb)
          acc[nb] = __builtin_amdgcn_mfma_f32_16x16x32_bf16(af, Bfrag[kk][nb], acc[nb], 0, 0, 0);
      }
      float p[4];
      #pragma unroll
      for (int r = 0; r < 4; ++r) {
        float s = 0.f;
        #pragma unroll
        for (int nb = 0; nb < 4; ++nb)
          s += fmaxf(acc[nb][r] + b1r[nb], 0.f) * w2r[nb];
        p[r] = s;
      }
      #pragma unroll
      for (int off = 1; off < 16; off <<= 1) {
        #pragma unroll
        for (int r = 0; r < 4; ++r) p[r] += __shfl_xor(p[r], off, 64);
      }
      if (m == 0) {
        #pragma unroll
        for (int r = 0; r < 4; ++r) sScoreP[w][mt * 16 + quad * 4 + r] = p[r];
      }
    }
    __syncthreads();

    if (t < 64) {
      float s = sScoreP[0][t] + sScoreP[1][t] + sScoreP[2][t] + sScoreP[3][t] + b2;
      sAw[t] = 1.f / (1.f + __expf(-s));
    }
    __syncthreads();

    // segment pooling: thread t owns channel t; batch sorted -> run-length flush
    float a_att = 0.f, a_sum = 0.f, a_max = -INFINITY;
    int seg = sBatch[0];
    int runlen = 0;
    for (int i = 0; i < nvalid; ++i) {
      int b = sBatch[i];
      if (b != seg) {
        atomicAdd(&attbuf[(size_t)seg * 256 + t], a_att);
        atomicAdd(&sumbuf[(size_t)seg * 256 + t], a_sum);
        atomicMax(&maxkey[(size_t)seg * 256 + t], fkey(a_max));
        if (t == 0) atomicAdd(&cntbuf[seg], (float)runlen);
        a_att = 0.f; a_sum = 0.f; a_max = -INFINITY; runlen = 0; seg = b;
      }
      float xv = bf2f(sX[i][t]);
      a_sum += xv;
      a_att += xv * sAw[i];
      a_max = fmaxf(a_max, xv);
      ++runlen;
    }
    atomicAdd(&attbuf[(size_t)seg * 256 + t], a_att);
    atomicAdd(&sumbuf[(size_t)seg * 256 + t], a_sum);
    atomicMax(&maxkey[(size_t)seg * 256 + t], fkey(a_max));
    if (t == 0) atomicAdd(&cntbuf[seg], (float)runlen);
    __syncthreads();   // protect sX/sBatch before next tile's staging
  }
}

// ---------------------------------------------------------------------------
// Final MLP: out[g] = relu(comb[g] @ W1f + b1f) @ W2f + b2f, 4 graphs/block
// (1024 blocks -> good latency hiding), rank-1-update formulation.
// ---------------------------------------------------------------------------
__global__ __launch_bounds__(256, 4)
void final_mlp_kernel(const float* __restrict__ attbuf, const float* __restrict__ sumbuf,
                      const unsigned* __restrict__ maxkey, const float* __restrict__ cntbuf,
                      const float* __restrict__ W1f, const float* __restrict__ b1f,
                      const float* __restrict__ W2f, const float* __restrict__ b2f,
                      float* __restrict__ out) {
  __shared__ float sComb[4 * 768];
  __shared__ float sHid[4 * 256];
  const int t = threadIdx.x;
  const int g0 = blockIdx.x * 4;

  for (int idx = t; idx < 4 * 768; idx += 256) {
    int g = idx / 768;
    int k = idx - g * 768;
    int gg = g0 + g;
    float cnt = cntbuf[gg];
    float v;
    if (k < 256) {
      v = attbuf[(size_t)gg * 256 + k];
    } else if (k < 512) {
      v = sumbuf[(size_t)gg * 256 + (k - 256)] / fmaxf(cnt, 1.f);
    } else {
      unsigned u = maxkey[(size_t)gg * 256 + (k - 512)];
      unsigned b = (u & 0x80000000u) ? (u & 0x7fffffffu) : ~u;
      v = (cnt > 0.f) ? __uint_as_float(b) : 0.f;   // empty segment -> 0
    }
    sComb[idx] = v;
  }
  __syncthreads();

  float acc[4] = {0, 0, 0, 0};
  #pragma unroll 4
  for (int k = 0; k < 768; ++k) {
    float wv = W1f[k * 256 + t];
    #pragma unroll
    for (int g = 0; g < 4; ++g) acc[g] = fmaf(sComb[g * 768 + k], wv, acc[g]);
  }
  float bb = b1f[t];
  #pragma unroll
  for (int g = 0; g < 4; ++g) sHid[g * 256 + t] = fmaxf(acc[g] + bb, 0.f);
  __syncthreads();

  float acc2[4] = {0, 0, 0, 0};
  #pragma unroll 4
  for (int k = 0; k < 256; ++k) {
    float wv = W2f[k * 256 + t];
    #pragma unroll
    for (int g = 0; g < 4; ++g) acc2[g] = fmaf(sHid[g * 256 + k], wv, acc2[g]);
  }
  float bo = b2f[t];
  #pragma unroll
  for (int g = 0; g < 4; ++g) out[(size_t)(g0 + g) * 256 + t] = acc2[g] + bo;
}

// ---------------------------------------------------------------------------
extern "C" void kernel_launch(void* const* d_in, const int* in_sizes, int n_in,
                              void* d_out, int out_size, void* d_ws, size_t ws_size,
                              hipStream_t stream) {
  const float* x   = (const float*)d_in[0];
  const int* batch = (const int*)d_in[1];
  const float* W1a = (const float*)d_in[2];
  const float* b1a = (const float*)d_in[3];
  const float* W2a = (const float*)d_in[4];
  const float* b2a = (const float*)d_in[5];
  const float* W1f = (const float*)d_in[6];
  const float* b1f = (const float*)d_in[7];
  const float* W2f = (const float*)d_in[8];
  const float* b2f = (const float*)d_in[9];
  float* out = (float*)d_out;

  const int N = in_sizes[0] / 256;
  const int G = out_size / 256;

  char* ws = (char*)d_ws;
  float* attbuf = (float*)ws;
  float* sumbuf = attbuf + (size_t)G * 256;
  unsigned* maxkey = (unsigned*)(sumbuf + (size_t)G * 256);
  float* cntbuf = (float*)(maxkey + (size_t)G * 256);
  unsigned short* packedB = (unsigned short*)(cntbuf + G);

  size_t zero_bytes = ((size_t)G * 256 * 3 + G) * sizeof(float);
  hipMemsetAsync(d_ws, 0, zero_bytes, stream);

  prep_b_kernel<<<256, 256, 0, stream>>>(W1a, packedB);

  int ntiles = (N + 63) / 64;
  phase_a_kernel<<<512, 256, 0, stream>>>(x, batch, packedB, b1a, W2a, b2a,
                                          attbuf, sumbuf, maxkey, cntbuf, N, ntiles);

  final_mlp_kernel<<<G / 4, 256, 0, stream>>>(attbuf, sumbuf, maxkey, cntbuf,
                                              W1f, b1f, W2f, b2f, out);
}